// Round 1
// baseline (267.712 us; speedup 1.0000x reference)
//
#include <hip/hip_runtime.h>

// RGCN_70566312673746: out[e,o] = (sum_j x[e,j]) * sum_r (1/cs[e,r]) * (sum_i W[r,i,o])
// E=100000, R=64, I=256, O=256. edge_index is UNUSED by the reference output.
//
// Structure:
//   K1 (wsum_kernel): W_sum[r,o] = sum_i W[r,i,o] into workspace (memset + atomics).
//   K2 (rgcn_main):   fused x row-sum + recip staging + register-tiled fp32 GEMM.
//     Per block: 64-row tile. LDS = W_sum 64KB + recipT 16KB = exactly 80KB
//     -> 2 blocks/CU so memory/LDS phases of neighboring blocks overlap.

constexpr int En = 100000;
constexpr int Rn = 64;
constexpr int In = 256;
constexpr int On = 256;

__global__ void wsum_kernel(const float* __restrict__ W, float* __restrict__ wsum) {
    const int r = blockIdx.x >> 3;      // 64 relations
    const int chunk = blockIdx.x & 7;   // 8 chunks of 32 i-values
    const int o = threadIdx.x;          // 256 output channels
    const float* base = W + ((size_t)r * In + (size_t)chunk * 32) * On + o;
    float s = 0.f;
#pragma unroll
    for (int i = 0; i < 32; ++i) s += base[(size_t)i * On];
    atomicAdd(&wsum[r * On + o], s);    // device-scope fp32 atomic
}

__global__ __launch_bounds__(256) void rgcn_main(const float* __restrict__ x,
                                                 const float* __restrict__ cs,
                                                 const float* __restrict__ wsum,
                                                 float* __restrict__ out) {
    __shared__ float ldsW[Rn * On];     // 64 KB, [r][o]
    __shared__ float recipT[Rn * 64];   // 16 KB, [r][row]; its first 64 floats
                                        // transiently hold the per-row x-sums

    const int t = threadIdx.x;
    const int R0 = blockIdx.x * 64;     // tile's first global row

    // ---- Stage W_sum -> LDS (coalesced float4), overlapped with Phase A ----
#pragma unroll
    for (int k = 0; k < 16; ++k) {
        const int f = k * 1024 + t * 4;
        *reinterpret_cast<float4*>(&ldsW[f]) =
            *reinterpret_cast<const float4*>(&wsum[f]);
    }

    // ---- Phase A: x row sums. Wave w, sweep s covers local row s*4+w.
    //      64 lanes x float4 = one full 256-float row, perfectly coalesced. ----
    const int wv = t >> 6;
    const int lane = t & 63;
#pragma unroll
    for (int s = 0; s < 16; ++s) {
        const int lr = s * 4 + wv;
        const int g = R0 + lr;
        float4 v = make_float4(0.f, 0.f, 0.f, 0.f);
        if (g < En)
            v = *reinterpret_cast<const float4*>(&x[(size_t)g * In + lane * 4]);
        float sum = v.x + v.y + v.z + v.w;
#pragma unroll
        for (int off = 32; off; off >>= 1) sum += __shfl_down(sum, off, 64);
        if (lane == 0) recipT[lr] = sum;   // deposit xsum in r=0 row
    }
    __syncthreads();

    // ---- Phase B1: read my 4 xsum values BEFORE they get overwritten; load cs ----
    const int q = t >> 4;   // t/16: row-within-sweep group
    const int m = t & 15;   // t%16: which 4 relations
    float xs[4];
    float4 c4[4];
#pragma unroll
    for (int s = 0; s < 4; ++s) {
        const int row = s * 16 + q;
        const int g = R0 + row;
        xs[s] = (g < En) ? recipT[row] : 0.f;
        c4[s] = make_float4(1.f, 1.f, 1.f, 1.f);
        if (g < En)
            c4[s] = *reinterpret_cast<const float4*>(&cs[(size_t)g * Rn + m * 4]);
    }
    __syncthreads();

    // ---- Phase B2: recipT[r][row] = xsum[row] / cs[row][r] (xsum folded in,
    //      so the epilogue is a pure store) ----
#pragma unroll
    for (int s = 0; s < 4; ++s) {
        const int row = s * 16 + q;
        recipT[(4 * m + 0) * 64 + row] = xs[s] / c4[s].x;
        recipT[(4 * m + 1) * 64 + row] = xs[s] / c4[s].y;
        recipT[(4 * m + 2) * 64 + row] = xs[s] / c4[s].z;
        recipT[(4 * m + 3) * 64 + row] = xs[s] / c4[s].w;
    }
    __syncthreads();

    // ---- GEMM: thread tile 8 rows x 8 cols (cols split tcol*4 and 128+tcol*4
    //      so every ds_read_b128 is consecutive-16B / broadcast -> conflict-free) ----
    const int trow = t >> 5;  // 0..7
    const int tcol = t & 31;  // 0..31
    float acc[8][8];
#pragma unroll
    for (int j = 0; j < 8; ++j)
#pragma unroll
        for (int k = 0; k < 8; ++k) acc[j][k] = 0.f;

#pragma unroll 4
    for (int r = 0; r < 64; ++r) {
        const float4 a0 = *reinterpret_cast<float4*>(&recipT[r * 64 + trow * 8]);
        const float4 a1 = *reinterpret_cast<float4*>(&recipT[r * 64 + trow * 8 + 4]);
        const float4 b0 = *reinterpret_cast<float4*>(&ldsW[r * 256 + tcol * 4]);
        const float4 b1 = *reinterpret_cast<float4*>(&ldsW[r * 256 + 128 + tcol * 4]);
        const float a[8] = {a0.x, a0.y, a0.z, a0.w, a1.x, a1.y, a1.z, a1.w};
        const float b[8] = {b0.x, b0.y, b0.z, b0.w, b1.x, b1.y, b1.z, b1.w};
#pragma unroll
        for (int j = 0; j < 8; ++j)
#pragma unroll
            for (int k = 0; k < 8; ++k)
                acc[j][k] = fmaf(a[j], b[k], acc[j][k]);
    }

    // ---- Epilogue: coalesced float4 stores ----
#pragma unroll
    for (int j = 0; j < 8; ++j) {
        const int g = R0 + trow * 8 + j;
        if (g < En) {
            const float4 o0 = make_float4(acc[j][0], acc[j][1], acc[j][2], acc[j][3]);
            const float4 o1 = make_float4(acc[j][4], acc[j][5], acc[j][6], acc[j][7]);
            *reinterpret_cast<float4*>(&out[(size_t)g * On + tcol * 4]) = o0;
            *reinterpret_cast<float4*>(&out[(size_t)g * On + 128 + tcol * 4]) = o1;
        }
    }
}

extern "C" void kernel_launch(void* const* d_in, const int* in_sizes, int n_in,
                              void* d_out, int out_size, void* d_ws, size_t ws_size,
                              hipStream_t stream) {
    const float* x  = (const float*)d_in[0];   // (E, I) fp32
    const float* cs = (const float*)d_in[1];   // (E, R) fp32
    const float* W  = (const float*)d_in[2];   // (R, I, O) fp32
    // d_in[3] = edge_index: unused by the reference output.
    float* wsum = (float*)d_ws;                // (R, O) fp32 scratch = 64 KB
    float* out  = (float*)d_out;               // (E, O) fp32

    hipMemsetAsync(wsum, 0, Rn * On * sizeof(float), stream);
    wsum_kernel<<<dim3(Rn * 8), dim3(256), 0, stream>>>(W, wsum);
    const int tiles = (En + 63) / 64;          // 1563
    rgcn_main<<<dim3(tiles), dim3(256), 0, stream>>>(x, cs, wsum, out);
}

// Round 2
// 239.534 us; speedup vs baseline: 1.1176x; 1.1176x over previous
//
#include <hip/hip_runtime.h>

// RGCN_70566312673746: out[e,o] = x_sum[e] * sum_r (1/cs[e,r]) * Wsum[r,o]
//   Wsum[r,o] = sum_i W[r,i,o].  E=100000, R=64, I=256, O=256.
//   edge_index is UNUSED by the reference output.
//
// Round-2 structure (bf16 MFMA path):
//   K1a wsum_partial: 256 blocks -> partial sums (no atomics/memset)
//   K1b wsum_combine: 64 blocks  -> WsumT bf16 [o][r] in ws (transposed once)
//   K2  rgcn_main:    64-row tile/block, 4 waves. Single barrier.
//       LDS: B^T 256x(64+8pad) bf16 = 36KB, A 64x72 bf16 = 9KB, xsum 256B
//       -> 45KB => 3 blocks/CU. GEMM = 32 MFMA(16x16x32 bf16) per wave.
//       Association matches np ref: (bf16(1/cs) @ bf16(Wsum)) * fp32 xsum.

constexpr int En = 100000;
constexpr int Rn = 64;
constexpr int In = 256;
constexpr int On = 256;

typedef short bf16x8 __attribute__((ext_vector_type(8)));
typedef float floatx4 __attribute__((ext_vector_type(4)));

// round-to-nearest-even fp32 -> bf16 bits (values are finite, no NaN path)
static __device__ __forceinline__ short f2bf(float f) {
    unsigned u = __builtin_bit_cast(unsigned, f);
    unsigned r = (u + 0x7FFFu + ((u >> 16) & 1u)) >> 16;
    return (short)r;
}

// ---- K1a: partial W sums. block b = r*4+q sums i in [q*64, q*64+64) ----
__global__ __launch_bounds__(256) void wsum_partial(const float* __restrict__ W,
                                                    float* __restrict__ partial) {
    const int b = blockIdx.x;          // 0..255
    const int r = b >> 2;
    const int qc = b & 3;
    const int o = threadIdx.x;
    const float* base = W + ((size_t)r * In + (size_t)qc * 64) * On + o;
    float s0 = 0.f, s1 = 0.f, s2 = 0.f, s3 = 0.f;
#pragma unroll
    for (int i = 0; i < 64; i += 4) {
        s0 += base[(size_t)(i + 0) * On];
        s1 += base[(size_t)(i + 1) * On];
        s2 += base[(size_t)(i + 2) * On];
        s3 += base[(size_t)(i + 3) * On];
    }
    partial[b * On + o] = (s0 + s1) + (s2 + s3);
}

// ---- K1b: combine 4 partials, write WsumT bf16 [o][r] (transposed) ----
__global__ __launch_bounds__(256) void wsum_combine(const float* __restrict__ partial,
                                                    short* __restrict__ wsumT) {
    const int r = blockIdx.x;          // 0..63
    const int o = threadIdx.x;
    const float* p = partial + (size_t)r * 4 * On + o;
    float s = (p[0] + p[On]) + (p[2 * On] + p[3 * On]);
    wsumT[o * Rn + r] = f2bf(s);       // 16K scattered 2B stores total: fine
}

// ---- K1 fallback (small ws): direct per-relation sum, 64 blocks ----
__global__ __launch_bounds__(256) void wsum_direct(const float* __restrict__ W,
                                                   short* __restrict__ wsumT) {
    const int r = blockIdx.x;
    const int o = threadIdx.x;
    const float* base = W + (size_t)r * In * On + o;
    float s0 = 0.f, s1 = 0.f, s2 = 0.f, s3 = 0.f;
#pragma unroll 16
    for (int i = 0; i < 256; i += 4) {
        s0 += base[(size_t)(i + 0) * On];
        s1 += base[(size_t)(i + 1) * On];
        s2 += base[(size_t)(i + 2) * On];
        s3 += base[(size_t)(i + 3) * On];
    }
    wsumT[o * Rn + r] = f2bf((s0 + s1) + (s2 + s3));
}

// ---- K2: main fused kernel ----
__global__ __launch_bounds__(256, 3) void rgcn_main(const float* __restrict__ x,
                                                    const float* __restrict__ cs,
                                                    const short* __restrict__ wsumT,
                                                    float* __restrict__ out) {
    // padded to 72 shorts/row (144B = 36 words stride -> <=2-way bank aliasing)
    __shared__ __align__(16) short BT[On][72];   // 36,864 B  B^T: [o][r]
    __shared__ __align__(16) short A[64][72];    //  9,216 B  A: [row][r]
    __shared__ float xs[64];

    const int t = threadIdx.x;
    const int R0 = blockIdx.x * 64;

    // ---- Stage B^T (same 32KB for every block; L2-resident) ----
    {
        const floatx4* wq = (const floatx4*)wsumT;   // 16B chunks
#pragma unroll
        for (int k = 0; k < 8; ++k) {
            const int ch = t + 256 * k;              // 0..2047
            const int o = ch >> 3, seg = ch & 7;
            *(floatx4*)((char*)&BT[o][0] + seg * 16) = wq[ch];
        }
    }

    // ---- Phase B: A[row][r] = bf16(1/cs[g][r])  (no xsum dependency) ----
    {
        const int m = t >> 2;              // 0..63 local row
        const int kc = (t & 3) << 4;       // 0,16,32,48
        const int g = R0 + m;
        float c[16];
#pragma unroll
        for (int j = 0; j < 16; ++j) c[j] = 1.f;
        if (g < En) {
            const float4* p = (const float4*)&cs[(size_t)g * Rn + kc];
            float4 c0 = p[0], c1 = p[1], c2 = p[2], c3 = p[3];
            c[0] = c0.x; c[1] = c0.y; c[2] = c0.z; c[3] = c0.w;
            c[4] = c1.x; c[5] = c1.y; c[6] = c1.z; c[7] = c1.w;
            c[8] = c2.x; c[9] = c2.y; c[10] = c2.z; c[11] = c2.w;
            c[12] = c3.x; c[13] = c3.y; c[14] = c3.z; c[15] = c3.w;
        }
        bf16x8 pk0, pk1;
#pragma unroll
        for (int j = 0; j < 8; ++j) {
            pk0[j] = (g < En) ? f2bf(1.f / c[j]) : (short)0;
            pk1[j] = (g < En) ? f2bf(1.f / c[8 + j]) : (short)0;
        }
        *(bf16x8*)&A[m][kc] = pk0;
        *(bf16x8*)&A[m][kc + 8] = pk1;
    }

    // ---- Phase A: fp32 row sums of x (wave per row sweep) ----
    {
        const int wv = t >> 6;
        const int lane = t & 63;
#pragma unroll
        for (int s = 0; s < 16; ++s) {
            const int lr = s * 4 + wv;
            const int g = R0 + lr;
            float4 v = make_float4(0.f, 0.f, 0.f, 0.f);
            if (g < En)
                v = *(const float4*)&x[(size_t)g * In + lane * 4];
            float sum = (v.x + v.y) + (v.z + v.w);
#pragma unroll
            for (int off = 32; off; off >>= 1) sum += __shfl_down(sum, off, 64);
            if (lane == 0) xs[lr] = sum;
        }
    }

    __syncthreads();   // the only barrier

    // ---- GEMM: wave w owns rows [16w,16w+16), all 256 cols; K=64 ----
    const int wave = t >> 6;
    const int ln = t & 63;
    const int m0 = wave * 16;
    const int lm = ln & 15;    // A-row / B-col within 16x16 tile
    const int q = ln >> 4;     // quad -> k-subchunk and C/D row group

    // A fragments: A[m=lm][k=q*8+j], k0 = 0 and 32
    const bf16x8 a0 = *(const bf16x8*)&A[m0 + lm][q * 8];
    const bf16x8 a1 = *(const bf16x8*)&A[m0 + lm][32 + q * 8];

    floatx4 acc[16];
#pragma unroll
    for (int tile = 0; tile < 16; ++tile) {
        const int o = tile * 16 + lm;
        const bf16x8 b0 = *(const bf16x8*)&BT[o][q * 8];
        const bf16x8 b1 = *(const bf16x8*)&BT[o][32 + q * 8];
        floatx4 c = {0.f, 0.f, 0.f, 0.f};
        c = __builtin_amdgcn_mfma_f32_16x16x32_bf16(a0, b0, c, 0, 0, 0);
        c = __builtin_amdgcn_mfma_f32_16x16x32_bf16(a1, b1, c, 0, 0, 0);
        acc[tile] = c;
    }

    // ---- Epilogue: scale by fp32 xsum, store. C/D: col=lm, row=q*4+reg ----
    float xr[4];
#pragma unroll
    for (int rg = 0; rg < 4; ++rg) xr[rg] = xs[m0 + q * 4 + rg];

#pragma unroll
    for (int tile = 0; tile < 16; ++tile) {
        const int col = tile * 16 + lm;
#pragma unroll
        for (int rg = 0; rg < 4; ++rg) {
            const int row = R0 + m0 + q * 4 + rg;
            if (row < En)
                out[(size_t)row * On + col] = acc[tile][rg] * xr[rg];
        }
    }
}

extern "C" void kernel_launch(void* const* d_in, const int* in_sizes, int n_in,
                              void* d_out, int out_size, void* d_ws, size_t ws_size,
                              hipStream_t stream) {
    const float* x  = (const float*)d_in[0];   // (E, I) fp32
    const float* cs = (const float*)d_in[1];   // (E, R) fp32
    const float* W  = (const float*)d_in[2];   // (R, I, O) fp32
    // d_in[3] = edge_index: unused by the reference output.
    float* out = (float*)d_out;

    short* wsumT = (short*)d_ws;                          // 32 KB: bf16 [o][r]
    float* partial = (float*)((char*)d_ws + 32768);       // 256 KB

    if (ws_size >= (size_t)(32768 + 256 * On * 4)) {
        wsum_partial<<<dim3(256), dim3(256), 0, stream>>>(W, partial);
        wsum_combine<<<dim3(64), dim3(256), 0, stream>>>(partial, wsumT);
    } else {
        wsum_direct<<<dim3(64), dim3(256), 0, stream>>>(W, wsumT);
    }

    const int tiles = (En + 63) / 64;   // 1563
    rgcn_main<<<dim3(tiles), dim3(256), 0, stream>>>(x, cs, wsumT, out);
}

// Round 3
// 231.182 us; speedup vs baseline: 1.1580x; 1.0361x over previous
//
#include <hip/hip_runtime.h>

// RGCN_70566312673746: out[e,o] = xsum[e] * sum_r (1/cs[e,r]) * Wsum[r,o]
//   Wsum[r,o] = sum_i W[r,i,o].  E=100000, R=64, I=256, O=256.
//   edge_index is UNUSED by the reference output.
//
// Round-3 structure — three barrier-free streaming kernels (R2 post-mortem:
// the fused 64-row block was latency-bound at 21% HBM / 8% VALU; its barrier
// + serialized load chains dominated; throughput scaled with occupancy):
//   K1 wsum_kernel: Wsum^T bf16 [o][r] via LDS reduce. 256 blocks x 1024.
//   K2 xsum_kernel: row sums of x, grid-stride, 32 waves/CU, 4 rows in flight.
//   K3 out_kernel:  TRANSPOSED MFMA D = W^T x recip^T so each lane holds 4
//      consecutive o of one e -> float4 stores. W^T frags hoisted into 128
//      VGPRs per wave (no LDS, no barriers, no ds_read in loop); cs->B frags
//      in registers with v_rcp_f32; 1-deep prefetch. 2048 resident waves.

constexpr int En = 100000;
constexpr int Rn = 64;
constexpr int In = 256;
constexpr int On = 256;
constexpr int TILES = En / 16;   // 6250, exact (no row guards needed in K3)

typedef short bf16x8 __attribute__((ext_vector_type(8)));
typedef float floatx4 __attribute__((ext_vector_type(4)));

// round-to-nearest-even fp32 -> bf16 bits (finite values only)
static __device__ __forceinline__ short f2bf(float f) {
    unsigned u = __builtin_bit_cast(unsigned, f);
    unsigned r = (u + 0x7FFFu + ((u >> 16) & 1u)) >> 16;
    return (short)r;
}

// ---- K1: Wsum^T[o][r] = bf16(sum_i W[r,i,o]).  block b: r=b>>2, o-half h=b&3.
//      1024 threads: o_local = t&63, i-chunk ic = t>>6 (16 i's each). ----
__global__ __launch_bounds__(1024) void wsum_kernel(const float* __restrict__ W,
                                                    short* __restrict__ wsumT) {
    __shared__ float red[16][65];
    const int r  = blockIdx.x >> 2;
    const int h  = blockIdx.x & 3;
    const int ol = threadIdx.x & 63;
    const int ic = threadIdx.x >> 6;
    const int o  = h * 64 + ol;
    const float* base = W + ((size_t)r * In + (size_t)ic * 16) * On + o;
    float s = 0.f;
#pragma unroll
    for (int i = 0; i < 16; ++i) s += base[(size_t)i * On];
    red[ic][ol] = s;
    __syncthreads();
    if (ic == 0) {
        float t = 0.f;
#pragma unroll
        for (int j = 0; j < 16; ++j) t += red[j][ol];
        wsumT[o * Rn + r] = f2bf(t);
    }
}

// ---- K2: xsum[e] = sum_j x[e,j].  Wave per row, 4 rows in flight. ----
__global__ __launch_bounds__(256) void xsum_kernel(const float* __restrict__ x,
                                                   float* __restrict__ xsum,
                                                   int xstride) {
    const int w    = (blockIdx.x * 256 + (int)threadIdx.x) >> 6;
    const int nw   = (gridDim.x * 256) >> 6;
    const int lane = threadIdx.x & 63;
    for (int base = w * 4; base < En; base += nw * 4) {
        float s[4];
#pragma unroll
        for (int u = 0; u < 4; ++u) {
            const int row = base + u;
            float4 v = make_float4(0.f, 0.f, 0.f, 0.f);
            if (row < En)
                v = *(const float4*)&x[(size_t)row * In + lane * 4];
            s[u] = (v.x + v.y) + (v.z + v.w);
        }
#pragma unroll
        for (int u = 0; u < 4; ++u) {
#pragma unroll
            for (int off = 32; off; off >>= 1) s[u] += __shfl_down(s[u], off, 64);
        }
        if (lane == 0) {
#pragma unroll
            for (int u = 0; u < 4; ++u)
                if (base + u < En) xsum[(size_t)(base + u) * xstride] = s[u];
        }
    }
}

// ---- K3: out rows.  Wave owns 16 e-rows/tile, grid-stride over 6250 tiles.
//      MFMA computes D[o][e] (A = W^T frags, B = recip frags):
//        lane (q = ln>>4, lm = ln&15): e = t*16+lm, o = ot*16 + q*4 + rg. ----
__global__ __launch_bounds__(256) void out_kernel(const float* __restrict__ cs,
                                                  const short* __restrict__ wsumT,
                                                  const float* __restrict__ xsum,
                                                  int xstride,
                                                  float* __restrict__ out) {
    const int gw = (blockIdx.x * 256 + (int)threadIdx.x) >> 6;
    const int nw = (gridDim.x * 256) >> 6;
    const int ln = threadIdx.x & 63;
    const int lm = ln & 15;
    const int q  = ln >> 4;

    // Hoist W^T fragments for all 16 o-tiles: A[m=o_local=lm][k=r=q*8+j]
    bf16x8 wa0[16], wa1[16];
#pragma unroll
    for (int ot = 0; ot < 16; ++ot) {
        const short* p = wsumT + ((ot * 16 + lm) * Rn + q * 8);
        wa0[ot] = *(const bf16x8*)p;          // r = q*8 .. q*8+7
        wa1[ot] = *(const bf16x8*)(p + 32);   // r = 32+q*8 ..
    }

    int t = gw;
    if (t >= TILES) return;
    float4 c0, c1, c2, c3;
    float xv;
    {
        const float* p = cs + (size_t)(t * 16 + lm) * Rn + q * 8;
        c0 = *(const float4*)p;        c1 = *(const float4*)(p + 4);
        c2 = *(const float4*)(p + 32); c3 = *(const float4*)(p + 36);
        xv = xsum[(size_t)(t * 16 + lm) * xstride];
    }
    while (true) {
        const int tn = t + nw;
        const float4 d0 = c0, d1 = c1, d2 = c2, d3 = c3;
        const float xs = xv;
        if (tn < TILES) {   // 1-deep prefetch of next tile's cs + xsum
            const float* p = cs + (size_t)(tn * 16 + lm) * Rn + q * 8;
            c0 = *(const float4*)p;        c1 = *(const float4*)(p + 4);
            c2 = *(const float4*)(p + 32); c3 = *(const float4*)(p + 36);
            xv = xsum[(size_t)(tn * 16 + lm) * xstride];
        }
        // B frags: B[k=r=q*8+j][n=e_local=lm] = bf16(1/cs[e][r])
        bf16x8 b0, b1;
        {
            const float rv[16] = {d0.x, d0.y, d0.z, d0.w, d1.x, d1.y, d1.z, d1.w,
                                  d2.x, d2.y, d2.z, d2.w, d3.x, d3.y, d3.z, d3.w};
#pragma unroll
            for (int j = 0; j < 8; ++j) {
                b0[j] = f2bf(__builtin_amdgcn_rcpf(rv[j]));
                b1[j] = f2bf(__builtin_amdgcn_rcpf(rv[8 + j]));
            }
        }
        float* orow = out + (size_t)(t * 16 + lm) * On + q * 4;
#pragma unroll
        for (int ot = 0; ot < 16; ++ot) {
            floatx4 acc = {0.f, 0.f, 0.f, 0.f};
            acc = __builtin_amdgcn_mfma_f32_16x16x32_bf16(wa0[ot], b0, acc, 0, 0, 0);
            acc = __builtin_amdgcn_mfma_f32_16x16x32_bf16(wa1[ot], b1, acc, 0, 0, 0);
            // D: row=q*4+rg -> o, col=lm -> e; 4 consecutive o => float4 store
            const float4 st = make_float4(acc[0] * xs, acc[1] * xs,
                                          acc[2] * xs, acc[3] * xs);
            *(float4*)(orow + ot * 16) = st;
        }
        if (tn >= TILES) break;
        t = tn;
    }
}

extern "C" void kernel_launch(void* const* d_in, const int* in_sizes, int n_in,
                              void* d_out, int out_size, void* d_ws, size_t ws_size,
                              hipStream_t stream) {
    const float* x  = (const float*)d_in[0];   // (E, I) fp32
    const float* cs = (const float*)d_in[1];   // (E, R) fp32
    const float* W  = (const float*)d_in[2];   // (R, I, O) fp32
    // d_in[3] = edge_index: unused by the reference output.
    float* out = (float*)d_out;

    short* wsumT = (short*)d_ws;               // 32 KB bf16 [o][r]
    float* xsum;
    int xstride;
    if (ws_size >= (size_t)(32768 + En * 4)) {
        xsum = (float*)((char*)d_ws + 32768);  // 400 KB
        xstride = 1;
    } else {
        // Fallback: park xsum in out[:,0]; K3 reads it (prefetched, each row
        // read only by the wave that later overwrites it) then overwrites.
        xsum = out;
        xstride = On;
    }

    wsum_kernel<<<dim3(256), dim3(1024), 0, stream>>>(W, wsumT);
    xsum_kernel<<<dim3(2048), dim3(256), 0, stream>>>(x, xsum, xstride);
    out_kernel<<<dim3(512), dim3(256), 0, stream>>>(cs, wsumT, xsum, xstride, out);
}